// Round 11
// baseline (272.206 us; speedup 1.0000x reference)
//
#include <hip/hip_runtime.h>

#define BN_EPS 1e-5f

typedef __attribute__((ext_vector_type(8))) __bf16 bf16x8;
typedef __attribute__((ext_vector_type(4))) float f32x4;

__device__ __forceinline__ unsigned short f2bf(float f) {
    unsigned int u = __float_as_uint(f);
    u = (u + 0x7fffu + ((u >> 16) & 1u)) >> 16;
    return (unsigned short)u;
}
__device__ __forceinline__ float bfLo(unsigned int w) { return __uint_as_float(w << 16); }
__device__ __forceinline__ float bfHi(unsigned int w) { return __uint_as_float(w & 0xffff0000u); }

__device__ __forceinline__ void accRow(float* acc, uint4 v) {
    acc[0] += bfLo(v.x); acc[1] += bfHi(v.x);
    acc[2] += bfLo(v.y); acc[3] += bfHi(v.y);
    acc[4] += bfLo(v.z); acc[5] += bfHi(v.z);
    acc[6] += bfLo(v.w); acc[7] += bfHi(v.w);
}
__device__ __forceinline__ void accRowBN(float* acc, uint4 v, const float* a8, const float* c8) {
    acc[0] += fmaxf(fmaf(bfLo(v.x), a8[0], c8[0]), 0.f);
    acc[1] += fmaxf(fmaf(bfHi(v.x), a8[1], c8[1]), 0.f);
    acc[2] += fmaxf(fmaf(bfLo(v.y), a8[2], c8[2]), 0.f);
    acc[3] += fmaxf(fmaf(bfHi(v.y), a8[3], c8[3]), 0.f);
    acc[4] += fmaxf(fmaf(bfLo(v.z), a8[4], c8[4]), 0.f);
    acc[5] += fmaxf(fmaf(bfHi(v.z), a8[5], c8[5]), 0.f);
    acc[6] += fmaxf(fmaf(bfLo(v.w), a8[6], c8[6]), 0.f);
    acc[7] += fmaxf(fmaf(bfHi(v.w), a8[7], c8[7]), 0.f);
}

// ===== one-time prep: x->bf16, swizzle 3 weights, AND degree histogram (grid-stride) =====
// Wsw[((ct*4+q)*64 + l)*8 + j] = bf16( W[q*32 + (l>>4)*8 + j][ct*16 + (l&15)] )
__global__ void convert_prep_hist(const float* __restrict__ x, unsigned short* __restrict__ hb,
                                  int total4,
                                  const float* __restrict__ W1, const float* __restrict__ W2,
                                  const float* __restrict__ W3,
                                  unsigned short* __restrict__ w1s, unsigned short* __restrict__ w2s,
                                  unsigned short* __restrict__ w3s,
                                  const int* __restrict__ dst, int* __restrict__ deg, int E) {
    int tid0 = blockIdx.x * blockDim.x + threadIdx.x;
    int stride = gridDim.x * blockDim.x;
    if (tid0 < 40960) {
        int idx = tid0;
        const float* W; unsigned short* O; int NOUT;
        if (idx < 16384)      { W = W1; O = w1s; NOUT = 128; }
        else if (idx < 32768) { W = W2; O = w2s; NOUT = 128; idx -= 16384; }
        else                  { W = W3; O = w3s; NOUT = 64;  idx -= 32768; }
        int j = idx & 7;
        int l = (idx >> 3) & 63;
        int q = (idx >> 9) & 3;
        int ct = idx >> 11;
        int k = q * 32 + ((l >> 4) & 3) * 8 + j;
        int c = ct * 16 + (l & 15);
        O[idx] = f2bf(W[(size_t)k * NOUT + c]);
    }
    for (int i = tid0; i < total4; i += stride) {
        float4 v = reinterpret_cast<const float4*>(x)[i];
        ushort4 o;
        o.x = f2bf(v.x); o.y = f2bf(v.y); o.z = f2bf(v.z); o.w = f2bf(v.w);
        reinterpret_cast<ushort4*>(hb)[i] = o;
    }
    for (int e = tid0; e < E; e += stride) atomicAdd(&deg[dst[e]], 1);
}

// ===== merged scan: chunk scan -> grid barrier -> top-scan -> rowptr/pos =====
__global__ void build_rowptr(const int* __restrict__ deg, int* __restrict__ rowptr,
                             int* __restrict__ pos, int* __restrict__ bsum,
                             int* __restrict__ arrive, int N, int E, int nChunks) {
    __shared__ int s[256];
    const int tid = threadIdx.x;
    const int b = blockIdx.x;
    const int i = b * 256 + tid;
    const int v = (i < N) ? deg[i] : 0;
    s[tid] = v;
    __syncthreads();
#pragma unroll
    for (int off = 1; off < 256; off <<= 1) {
        int t = (tid >= off) ? s[tid - off] : 0;
        __syncthreads();
        s[tid] += t;
        __syncthreads();
    }
    const int incl = s[tid];
    if (tid == 255) bsum[b] = incl;
    __threadfence();
    __syncthreads();
    if (tid == 0) {
        __hip_atomic_fetch_add(arrive, 1, __ATOMIC_ACQ_REL, __HIP_MEMORY_SCOPE_AGENT);
        while (__hip_atomic_load(arrive, __ATOMIC_ACQUIRE, __HIP_MEMORY_SCOPE_AGENT) < nChunks) {}
    }
    __syncthreads();
    int val = (tid < b)
                  ? __hip_atomic_load(&bsum[tid], __ATOMIC_RELAXED, __HIP_MEMORY_SCOPE_AGENT)
                  : 0;
    s[tid] = val;
    __syncthreads();
#pragma unroll
    for (int off = 128; off > 0; off >>= 1) {
        if (tid < off) s[tid] += s[tid + off];
        __syncthreads();
    }
    const int base = s[0];
    if (i < N) {
        int r = incl - v + base;
        rowptr[i] = r;
        pos[i] = r;
    }
    if (b == 0 && tid == 0) rowptr[N] = E;
}

// ===== CSR fill: one thread per edge (max TLP for the dependent atomic+scatter) =====
__global__ void fill_kernel(const int* __restrict__ src, const int* __restrict__ dst,
                            int* __restrict__ pos, int* __restrict__ col, int E) {
    int e = blockIdx.x * blockDim.x + threadIdx.x;
    if (e < E) {
        int slot = atomicAdd(&pos[dst[e]], 1);
        col[slot] = src[e];
    }
}

// ============ plain gather (layer 1): agg[i] = h[i] + sum_j h[j], 8-edge unroll ============
__global__ void gather_agg_bf(const unsigned short* __restrict__ h,
                              const int* __restrict__ rowptr, const int* __restrict__ col,
                              unsigned short* __restrict__ agg, int N) {
    int t = blockIdx.x * blockDim.x + threadIdx.x;
    int node = t >> 4;
    if (node >= N) return;
    int part = (t & 15) * 8;
    const unsigned short* hp = h + part;
    const int beg = rowptr[node], end = rowptr[node + 1];

    float acc[8];
    {
        uint4 sv = *reinterpret_cast<const uint4*>(hp + (size_t)node * 128);
        acc[0] = bfLo(sv.x); acc[1] = bfHi(sv.x);
        acc[2] = bfLo(sv.y); acc[3] = bfHi(sv.y);
        acc[4] = bfLo(sv.z); acc[5] = bfHi(sv.z);
        acc[6] = bfLo(sv.w); acc[7] = bfHi(sv.w);
    }
    int e = beg;
    for (; e + 7 < end; e += 8) {
        uint4 v0 = *reinterpret_cast<const uint4*>(hp + (size_t)col[e] * 128);
        uint4 v1 = *reinterpret_cast<const uint4*>(hp + (size_t)col[e + 1] * 128);
        uint4 v2 = *reinterpret_cast<const uint4*>(hp + (size_t)col[e + 2] * 128);
        uint4 v3 = *reinterpret_cast<const uint4*>(hp + (size_t)col[e + 3] * 128);
        uint4 v4 = *reinterpret_cast<const uint4*>(hp + (size_t)col[e + 4] * 128);
        uint4 v5 = *reinterpret_cast<const uint4*>(hp + (size_t)col[e + 5] * 128);
        uint4 v6 = *reinterpret_cast<const uint4*>(hp + (size_t)col[e + 6] * 128);
        uint4 v7 = *reinterpret_cast<const uint4*>(hp + (size_t)col[e + 7] * 128);
        accRow(acc, v0); accRow(acc, v1); accRow(acc, v2); accRow(acc, v3);
        accRow(acc, v4); accRow(acc, v5); accRow(acc, v6); accRow(acc, v7);
    }
    for (; e + 3 < end; e += 4) {
        uint4 v0 = *reinterpret_cast<const uint4*>(hp + (size_t)col[e] * 128);
        uint4 v1 = *reinterpret_cast<const uint4*>(hp + (size_t)col[e + 1] * 128);
        uint4 v2 = *reinterpret_cast<const uint4*>(hp + (size_t)col[e + 2] * 128);
        uint4 v3 = *reinterpret_cast<const uint4*>(hp + (size_t)col[e + 3] * 128);
        accRow(acc, v0); accRow(acc, v1); accRow(acc, v2); accRow(acc, v3);
    }
    for (; e < end; ++e)
        accRow(acc, *reinterpret_cast<const uint4*>(hp + (size_t)col[e] * 128));

    uint4 o;
    o.x = (unsigned int)f2bf(acc[0]) | ((unsigned int)f2bf(acc[1]) << 16);
    o.y = (unsigned int)f2bf(acc[2]) | ((unsigned int)f2bf(acc[3]) << 16);
    o.z = (unsigned int)f2bf(acc[4]) | ((unsigned int)f2bf(acc[5]) << 16);
    o.w = (unsigned int)f2bf(acc[6]) | ((unsigned int)f2bf(acc[7]) << 16);
    *reinterpret_cast<uint4*>(agg + (size_t)node * 128 + part) = o;
}

// ============ BN+ReLU-fused gather (layer 2), 8-edge unroll ============
__global__ void gather_bn_agg(const unsigned short* __restrict__ raw,
                              const float* __restrict__ sumsPad, const float* __restrict__ sqsPad,
                              const float* __restrict__ g, const float* __restrict__ be,
                              const int* __restrict__ rowptr, const int* __restrict__ col,
                              unsigned short* __restrict__ agg, int N, float invN) {
    int t = blockIdx.x * blockDim.x + threadIdx.x;
    int node = t >> 4;
    if (node >= N) return;
    int part = (t & 15) * 8;
    const unsigned short* rp = raw + part;
    float a8[8], c8[8];
#pragma unroll
    for (int k = 0; k < 8; ++k) {
        int c = part + k;
        float m = sumsPad[c * 16] * invN;
        float v = sqsPad[c * 16] * invN - m * m;
        float ai = g[c] * rsqrtf(v + BN_EPS);
        a8[k] = ai;
        c8[k] = be[c] - m * ai;
    }
    const int beg = rowptr[node], end = rowptr[node + 1];
    float acc[8] = {0.f, 0.f, 0.f, 0.f, 0.f, 0.f, 0.f, 0.f};
    accRowBN(acc, *reinterpret_cast<const uint4*>(rp + (size_t)node * 128), a8, c8);  // self
    int e = beg;
    for (; e + 7 < end; e += 8) {
        uint4 v0 = *reinterpret_cast<const uint4*>(rp + (size_t)col[e] * 128);
        uint4 v1 = *reinterpret_cast<const uint4*>(rp + (size_t)col[e + 1] * 128);
        uint4 v2 = *reinterpret_cast<const uint4*>(rp + (size_t)col[e + 2] * 128);
        uint4 v3 = *reinterpret_cast<const uint4*>(rp + (size_t)col[e + 3] * 128);
        uint4 v4 = *reinterpret_cast<const uint4*>(rp + (size_t)col[e + 4] * 128);
        uint4 v5 = *reinterpret_cast<const uint4*>(rp + (size_t)col[e + 5] * 128);
        uint4 v6 = *reinterpret_cast<const uint4*>(rp + (size_t)col[e + 6] * 128);
        uint4 v7 = *reinterpret_cast<const uint4*>(rp + (size_t)col[e + 7] * 128);
        accRowBN(acc, v0, a8, c8); accRowBN(acc, v1, a8, c8);
        accRowBN(acc, v2, a8, c8); accRowBN(acc, v3, a8, c8);
        accRowBN(acc, v4, a8, c8); accRowBN(acc, v5, a8, c8);
        accRowBN(acc, v6, a8, c8); accRowBN(acc, v7, a8, c8);
    }
    for (; e + 3 < end; e += 4) {
        uint4 v0 = *reinterpret_cast<const uint4*>(rp + (size_t)col[e] * 128);
        uint4 v1 = *reinterpret_cast<const uint4*>(rp + (size_t)col[e + 1] * 128);
        uint4 v2 = *reinterpret_cast<const uint4*>(rp + (size_t)col[e + 2] * 128);
        uint4 v3 = *reinterpret_cast<const uint4*>(rp + (size_t)col[e + 3] * 128);
        accRowBN(acc, v0, a8, c8); accRowBN(acc, v1, a8, c8);
        accRowBN(acc, v2, a8, c8); accRowBN(acc, v3, a8, c8);
    }
    for (; e < end; ++e)
        accRowBN(acc, *reinterpret_cast<const uint4*>(rp + (size_t)col[e] * 128), a8, c8);

    uint4 o;
    o.x = (unsigned int)f2bf(acc[0]) | ((unsigned int)f2bf(acc[1]) << 16);
    o.y = (unsigned int)f2bf(acc[2]) | ((unsigned int)f2bf(acc[3]) << 16);
    o.z = (unsigned int)f2bf(acc[4]) | ((unsigned int)f2bf(acc[5]) << 16);
    o.w = (unsigned int)f2bf(acc[6]) | ((unsigned int)f2bf(acc[7]) << 16);
    *reinterpret_cast<uint4*>(agg + (size_t)node * 128 + part) = o;
}

// ========== MFMA GEMM (NOUT=128) + bias + fused column stats; bf16 raw out ==========
__global__ __launch_bounds__(256) void gemm128_stats(const unsigned short* __restrict__ A,
                                                     const unsigned short* __restrict__ Wsw,
                                                     const float* __restrict__ bias,
                                                     unsigned short* __restrict__ outb,
                                                     float* __restrict__ sumsPad,
                                                     float* __restrict__ sqsPad, int N) {
    __shared__ float red[2][4][128];
    const int lane = threadIdx.x & 63;
    const int w = threadIdx.x >> 6;
    const int r0 = blockIdx.x * 64 + w * 16;
    int arow = r0 + (lane & 15);
    if (arow >= N) arow = N - 1;
    const int kb = lane >> 4;
    const unsigned short* ap = A + (size_t)arow * 128 + kb * 8;

    bf16x8 a[4];
#pragma unroll
    for (int q = 0; q < 4; ++q) a[q] = *reinterpret_cast<const bf16x8*>(ap + q * 32);

    f32x4 acc[8];
#pragma unroll
    for (int ct = 0; ct < 8; ++ct) acc[ct] = (f32x4){0.f, 0.f, 0.f, 0.f};

    const bf16x8* wp = reinterpret_cast<const bf16x8*>(Wsw) + lane;
#pragma unroll
    for (int ct = 0; ct < 8; ++ct)
#pragma unroll
        for (int q = 0; q < 4; ++q)
            acc[ct] = __builtin_amdgcn_mfma_f32_16x16x32_bf16(a[q], wp[(ct * 4 + q) * 64],
                                                              acc[ct], 0, 0, 0);

    const int crow0 = r0 + (lane >> 4) * 4;
    const int ccol = lane & 15;
#pragma unroll
    for (int ct = 0; ct < 8; ++ct) {
        int c = ct * 16 + ccol;
        float bv = bias[c];
        float s = 0.f, qq = 0.f;
#pragma unroll
        for (int j = 0; j < 4; ++j) {
            int r = crow0 + j;
            if (r < N) {
                float o = acc[ct][j] + bv;
                outb[(size_t)r * 128 + c] = f2bf(o);
                s += o; qq += o * o;
            }
        }
        s += __shfl_xor(s, 16); s += __shfl_xor(s, 32);
        qq += __shfl_xor(qq, 16); qq += __shfl_xor(qq, 32);
        if (lane < 16) { red[0][w][c] = s; red[1][w][c] = qq; }
    }
    __syncthreads();
    int tid = threadIdx.x;
    if (tid < 128) {
        float S = red[0][0][tid] + red[0][1][tid] + red[0][2][tid] + red[0][3][tid];
        atomicAdd(&sumsPad[tid * 16], S);
    } else {
        int c = tid - 128;
        float Q = red[1][0][c] + red[1][1][c] + red[1][2][c] + red[1][3][c];
        atomicAdd(&sqsPad[c * 16], Q);
    }
}

// ========== MFMA GEMM (NOUT=64) with inline BN2+ReLU on A; M = relu(bn(raw)) @ W3 (NO bias) ==========
__global__ __launch_bounds__(256) void gemm64_bn(const unsigned short* __restrict__ raw,
                                                 const float* __restrict__ sumsPad,
                                                 const float* __restrict__ sqsPad,
                                                 const float* __restrict__ g,
                                                 const float* __restrict__ be,
                                                 const unsigned short* __restrict__ Wsw,
                                                 unsigned short* __restrict__ M, int N,
                                                 float invN) {
    const int lane = threadIdx.x & 63;
    const int w = threadIdx.x >> 6;
    const int r0 = blockIdx.x * 64 + w * 16;
    int arow = r0 + (lane & 15);
    if (arow >= N) arow = N - 1;
    const int kb = lane >> 4;
    const unsigned short* ap = raw + (size_t)arow * 128 + kb * 8;

    bf16x8 a[4];
#pragma unroll
    for (int q = 0; q < 4; ++q) {
        uint4 rv = *reinterpret_cast<const uint4*>(ap + q * 32);
        float hh[8] = {bfLo(rv.x), bfHi(rv.x), bfLo(rv.y), bfHi(rv.y),
                       bfLo(rv.z), bfHi(rv.z), bfLo(rv.w), bfHi(rv.w)};
        unsigned int pk[4];
#pragma unroll
        for (int p = 0; p < 4; ++p) {
            unsigned int lohi[2];
#pragma unroll
            for (int hl = 0; hl < 2; ++hl) {
                int j = p * 2 + hl;
                int c = q * 32 + kb * 8 + j;
                float mcol = sumsPad[c * 16] * invN;
                float var = sqsPad[c * 16] * invN - mcol * mcol;
                float ai = g[c] * rsqrtf(var + BN_EPS);
                float ci = be[c] - mcol * ai;
                lohi[hl] = f2bf(fmaxf(fmaf(hh[j], ai, ci), 0.f));
            }
            pk[p] = lohi[0] | (lohi[1] << 16);
        }
        uint4 hp;
        hp.x = pk[0]; hp.y = pk[1]; hp.z = pk[2]; hp.w = pk[3];
        a[q] = *reinterpret_cast<bf16x8*>(&hp);
    }

    f32x4 acc[4];
#pragma unroll
    for (int ct = 0; ct < 4; ++ct) acc[ct] = (f32x4){0.f, 0.f, 0.f, 0.f};

    const bf16x8* wp = reinterpret_cast<const bf16x8*>(Wsw) + lane;
#pragma unroll
    for (int ct = 0; ct < 4; ++ct)
#pragma unroll
        for (int q = 0; q < 4; ++q)
            acc[ct] = __builtin_amdgcn_mfma_f32_16x16x32_bf16(a[q], wp[(ct * 4 + q) * 64],
                                                              acc[ct], 0, 0, 0);

    const int crow0 = r0 + (lane >> 4) * 4;
    const int ccol = lane & 15;
#pragma unroll
    for (int ct = 0; ct < 4; ++ct) {
        int c = ct * 16 + ccol;
#pragma unroll
        for (int j = 0; j < 4; ++j) {
            int r = crow0 + j;
            if (r < N) M[(size_t)r * 64 + c] = f2bf(acc[ct][j]);
        }
    }
}

// ========== layer-3 gather on M (64-wide) + bias + log_softmax; 8 lanes/node, 8-edge unroll ==========
__global__ void gather64_lsm(const unsigned short* __restrict__ M,
                             const int* __restrict__ rowptr, const int* __restrict__ col,
                             const float* __restrict__ bias, float* __restrict__ out, int N) {
    int t = blockIdx.x * blockDim.x + threadIdx.x;
    int node = t >> 3;
    if (node >= N) return;
    int part = (t & 7) * 8;
    const unsigned short* mp = M + part;
    const int beg = rowptr[node], end = rowptr[node + 1];

    float acc[8];
    {
        uint4 sv = *reinterpret_cast<const uint4*>(mp + (size_t)node * 64);
        acc[0] = bfLo(sv.x); acc[1] = bfHi(sv.x);
        acc[2] = bfLo(sv.y); acc[3] = bfHi(sv.y);
        acc[4] = bfLo(sv.z); acc[5] = bfHi(sv.z);
        acc[6] = bfLo(sv.w); acc[7] = bfHi(sv.w);
    }
    int e = beg;
    for (; e + 7 < end; e += 8) {
        uint4 v0 = *reinterpret_cast<const uint4*>(mp + (size_t)col[e] * 64);
        uint4 v1 = *reinterpret_cast<const uint4*>(mp + (size_t)col[e + 1] * 64);
        uint4 v2 = *reinterpret_cast<const uint4*>(mp + (size_t)col[e + 2] * 64);
        uint4 v3 = *reinterpret_cast<const uint4*>(mp + (size_t)col[e + 3] * 64);
        uint4 v4 = *reinterpret_cast<const uint4*>(mp + (size_t)col[e + 4] * 64);
        uint4 v5 = *reinterpret_cast<const uint4*>(mp + (size_t)col[e + 5] * 64);
        uint4 v6 = *reinterpret_cast<const uint4*>(mp + (size_t)col[e + 6] * 64);
        uint4 v7 = *reinterpret_cast<const uint4*>(mp + (size_t)col[e + 7] * 64);
        accRow(acc, v0); accRow(acc, v1); accRow(acc, v2); accRow(acc, v3);
        accRow(acc, v4); accRow(acc, v5); accRow(acc, v6); accRow(acc, v7);
    }
    for (; e + 3 < end; e += 4) {
        uint4 v0 = *reinterpret_cast<const uint4*>(mp + (size_t)col[e] * 64);
        uint4 v1 = *reinterpret_cast<const uint4*>(mp + (size_t)col[e + 1] * 64);
        uint4 v2 = *reinterpret_cast<const uint4*>(mp + (size_t)col[e + 2] * 64);
        uint4 v3 = *reinterpret_cast<const uint4*>(mp + (size_t)col[e + 3] * 64);
        accRow(acc, v0); accRow(acc, v1); accRow(acc, v2); accRow(acc, v3);
    }
    for (; e < end; ++e)
        accRow(acc, *reinterpret_cast<const uint4*>(mp + (size_t)col[e] * 64));

#pragma unroll
    for (int k = 0; k < 8; ++k) acc[k] += bias[part + k];

    float m = acc[0];
#pragma unroll
    for (int k = 1; k < 8; ++k) m = fmaxf(m, acc[k]);
#pragma unroll
    for (int off = 1; off < 8; off <<= 1) m = fmaxf(m, __shfl_xor(m, off));
    float s = 0.f;
#pragma unroll
    for (int k = 0; k < 8; ++k) s += __expf(acc[k] - m);
#pragma unroll
    for (int off = 1; off < 8; off <<= 1) s += __shfl_xor(s, off);
    float ml = m + __logf(s);

    float4 o0, o1;
    o0.x = acc[0] - ml; o0.y = acc[1] - ml; o0.z = acc[2] - ml; o0.w = acc[3] - ml;
    o1.x = acc[4] - ml; o1.y = acc[5] - ml; o1.z = acc[6] - ml; o1.w = acc[7] - ml;
    float* op = out + (size_t)node * 64 + part;
    *reinterpret_cast<float4*>(op) = o0;
    *reinterpret_cast<float4*>(op + 4) = o1;
}

extern "C" void kernel_launch(void* const* d_in, const int* in_sizes, int n_in,
                              void* d_out, int out_size, void* d_ws, size_t ws_size,
                              hipStream_t stream) {
    const float* x   = (const float*)d_in[0];
    const int*   ei  = (const int*)d_in[1];
    const float* W1  = (const float*)d_in[2];
    const float* b1  = (const float*)d_in[3];
    const float* g1  = (const float*)d_in[4];
    const float* be1 = (const float*)d_in[5];
    const float* W2  = (const float*)d_in[6];
    const float* b2  = (const float*)d_in[7];
    const float* g2  = (const float*)d_in[8];
    const float* be2 = (const float*)d_in[9];
    const float* W3  = (const float*)d_in[10];
    const float* b3  = (const float*)d_in[11];

    const int N = in_sizes[0] / 128;
    const int E = in_sizes[1] / 2;
    const int* src = ei;
    const int* dst = ei + E;

    // ---- workspace carve-up; [statsPad|cnts|deg] is one memset region ----
    float* statsPad = (float*)d_ws;                 // 4 x 2048 (stride-16 cols)
    float* sums1 = statsPad;
    float* sqs1  = statsPad + 2048;
    float* sums2 = statsPad + 4096;
    float* sqs2  = statsPad + 6144;
    int* cnts   = (int*)(statsPad + 8192);          // 64 (grid-barrier counters)
    int* deg    = cnts + 64;                        // N
    int* pos    = deg + N;                          // N
    int* rowptr = pos + N;                          // N+1
    int* bsum   = rowptr + N + 1;                   // 256
    int* colidx = bsum + 256;                       // E
    unsigned short* hb   = (unsigned short*)(colidx + E);   // N*128 bf16 (x)
    unsigned short* rawb = hb + (size_t)N * 128;            // N*128 bf16 (gemm raw out)
    unsigned short* agb  = rawb + (size_t)N * 128;          // N*128 bf16 (agg)
    unsigned short* m3   = agb + (size_t)N * 128;           // N*64 bf16 (layer3 pre-agg)
    unsigned short* w1s  = m3 + (size_t)N * 64;             // 16384
    unsigned short* w2s  = w1s + 16384;                     // 16384
    unsigned short* w3s  = w2s + 16384;                     // 8192

    const int nChunks = (N + 255) / 256;
    const int eBlocks = (E + 255) / 256;
    const int gemmBlocks = (N + 63) / 64;
    const int gatherBlocks = (N * 16 + 255) / 256;
    const int gather64Blocks = (N * 8 + 255) / 256;
    const int total4 = N * 128 / 4;
    const float invN = 1.0f / N;

    // ---- one memset: stats + counters + deg ----
    hipMemsetAsync(statsPad, 0, 8192 * sizeof(float) + (64 + (size_t)N) * sizeof(int), stream);

    // ---- prep (x->bf16, W swizzle, degree hist); merged scan; wide fill ----
    convert_prep_hist<<<2048, 256, 0, stream>>>(x, hb, total4, W1, W2, W3, w1s, w2s, w3s,
                                                dst, deg, E);
    build_rowptr<<<nChunks, 256, 0, stream>>>(deg, rowptr, pos, bsum, cnts, N, E, nChunks);
    fill_kernel<<<eBlocks, 256, 0, stream>>>(src, dst, pos, colidx, E);

    // ---- layer 1 ----
    gather_agg_bf<<<gatherBlocks, 256, 0, stream>>>(hb, rowptr, colidx, agb, N);
    gemm128_stats<<<gemmBlocks, 256, 0, stream>>>(agb, w1s, b1, rawb, sums1, sqs1, N);

    // ---- layer 2 (BN1+ReLU fused into gather) ----
    gather_bn_agg<<<gatherBlocks, 256, 0, stream>>>(rawb, sums1, sqs1, g1, be1, rowptr, colidx,
                                                    agb, N, invN);
    gemm128_stats<<<gemmBlocks, 256, 0, stream>>>(agb, w2s, b2, rawb, sums2, sqs2, N);

    // ---- layer 3: GEMM first (BN2+ReLU inline), then 64-wide gather + bias + lsm ----
    gemm64_bn<<<gemmBlocks, 256, 0, stream>>>(rawb, sums2, sqs2, g2, be2, w3s, m3, N, invN);
    gather64_lsm<<<gather64Blocks, 256, 0, stream>>>(m3, rowptr, colidx, b3, (float*)d_out, N);
}

// Round 12
// 263.973 us; speedup vs baseline: 1.0312x; 1.0312x over previous
//
#include <hip/hip_runtime.h>

#define BN_EPS 1e-5f

typedef __attribute__((ext_vector_type(8))) __bf16 bf16x8;
typedef __attribute__((ext_vector_type(4))) float f32x4;

__device__ __forceinline__ unsigned short f2bf(float f) {
    unsigned int u = __float_as_uint(f);
    u = (u + 0x7fffu + ((u >> 16) & 1u)) >> 16;
    return (unsigned short)u;
}
__device__ __forceinline__ float bfLo(unsigned int w) { return __uint_as_float(w << 16); }
__device__ __forceinline__ float bfHi(unsigned int w) { return __uint_as_float(w & 0xffff0000u); }

__device__ __forceinline__ void accRow(float* acc, uint4 v) {
    acc[0] += bfLo(v.x); acc[1] += bfHi(v.x);
    acc[2] += bfLo(v.y); acc[3] += bfHi(v.y);
    acc[4] += bfLo(v.z); acc[5] += bfHi(v.z);
    acc[6] += bfLo(v.w); acc[7] += bfHi(v.w);
}
__device__ __forceinline__ void accRowBN(float* acc, uint4 v, const float* a8, const float* c8) {
    acc[0] += fmaxf(fmaf(bfLo(v.x), a8[0], c8[0]), 0.f);
    acc[1] += fmaxf(fmaf(bfHi(v.x), a8[1], c8[1]), 0.f);
    acc[2] += fmaxf(fmaf(bfLo(v.y), a8[2], c8[2]), 0.f);
    acc[3] += fmaxf(fmaf(bfHi(v.y), a8[3], c8[3]), 0.f);
    acc[4] += fmaxf(fmaf(bfLo(v.z), a8[4], c8[4]), 0.f);
    acc[5] += fmaxf(fmaf(bfHi(v.z), a8[5], c8[5]), 0.f);
    acc[6] += fmaxf(fmaf(bfLo(v.w), a8[6], c8[6]), 0.f);
    acc[7] += fmaxf(fmaf(bfHi(v.w), a8[7], c8[7]), 0.f);
}

// ===== one-time prep: x->bf16, swizzle 3 weights, AND degree histogram (grid-stride) =====
// Wsw[((ct*4+q)*64 + l)*8 + j] = bf16( W[q*32 + (l>>4)*8 + j][ct*16 + (l&15)] )
__global__ void convert_prep_hist(const float* __restrict__ x, unsigned short* __restrict__ hb,
                                  int total4,
                                  const float* __restrict__ W1, const float* __restrict__ W2,
                                  const float* __restrict__ W3,
                                  unsigned short* __restrict__ w1s, unsigned short* __restrict__ w2s,
                                  unsigned short* __restrict__ w3s,
                                  const int* __restrict__ dst, int* __restrict__ deg, int E) {
    int tid0 = blockIdx.x * blockDim.x + threadIdx.x;
    int stride = gridDim.x * blockDim.x;
    if (tid0 < 40960) {
        int idx = tid0;
        const float* W; unsigned short* O; int NOUT;
        if (idx < 16384)      { W = W1; O = w1s; NOUT = 128; }
        else if (idx < 32768) { W = W2; O = w2s; NOUT = 128; idx -= 16384; }
        else                  { W = W3; O = w3s; NOUT = 64;  idx -= 32768; }
        int j = idx & 7;
        int l = (idx >> 3) & 63;
        int q = (idx >> 9) & 3;
        int ct = idx >> 11;
        int k = q * 32 + ((l >> 4) & 3) * 8 + j;
        int c = ct * 16 + (l & 15);
        O[idx] = f2bf(W[(size_t)k * NOUT + c]);
    }
    for (int i = tid0; i < total4; i += stride) {
        float4 v = reinterpret_cast<const float4*>(x)[i];
        ushort4 o;
        o.x = f2bf(v.x); o.y = f2bf(v.y); o.z = f2bf(v.z); o.w = f2bf(v.w);
        reinterpret_cast<ushort4*>(hb)[i] = o;
    }
    for (int e = tid0; e < E; e += stride) atomicAdd(&deg[dst[e]], 1);
}

// ===== merged scan: chunk scan -> grid barrier -> top-scan -> rowptr/pos =====
__global__ void build_rowptr(const int* __restrict__ deg, int* __restrict__ rowptr,
                             int* __restrict__ pos, int* __restrict__ bsum,
                             int* __restrict__ arrive, int N, int E, int nChunks) {
    __shared__ int s[256];
    const int tid = threadIdx.x;
    const int b = blockIdx.x;
    const int i = b * 256 + tid;
    const int v = (i < N) ? deg[i] : 0;
    s[tid] = v;
    __syncthreads();
#pragma unroll
    for (int off = 1; off < 256; off <<= 1) {
        int t = (tid >= off) ? s[tid - off] : 0;
        __syncthreads();
        s[tid] += t;
        __syncthreads();
    }
    const int incl = s[tid];
    if (tid == 255) bsum[b] = incl;
    __threadfence();
    __syncthreads();
    if (tid == 0) {
        __hip_atomic_fetch_add(arrive, 1, __ATOMIC_ACQ_REL, __HIP_MEMORY_SCOPE_AGENT);
        while (__hip_atomic_load(arrive, __ATOMIC_ACQUIRE, __HIP_MEMORY_SCOPE_AGENT) < nChunks) {}
    }
    __syncthreads();
    int val = (tid < b)
                  ? __hip_atomic_load(&bsum[tid], __ATOMIC_RELAXED, __HIP_MEMORY_SCOPE_AGENT)
                  : 0;
    s[tid] = val;
    __syncthreads();
#pragma unroll
    for (int off = 128; off > 0; off >>= 1) {
        if (tid < off) s[tid] += s[tid + off];
        __syncthreads();
    }
    const int base = s[0];
    if (i < N) {
        int r = incl - v + base;
        rowptr[i] = r;
        pos[i] = r;
    }
    if (b == 0 && tid == 0) rowptr[N] = E;
}

// ===== CSR fill: one thread per edge (max TLP for the dependent atomic+scatter) =====
__global__ void fill_kernel(const int* __restrict__ src, const int* __restrict__ dst,
                            int* __restrict__ pos, int* __restrict__ col, int E) {
    int e = blockIdx.x * blockDim.x + threadIdx.x;
    if (e < E) {
        int slot = atomicAdd(&pos[dst[e]], 1);
        col[slot] = src[e];
    }
}

// ============ plain gather (layer 1): agg[i] = h[i] + sum_j h[j], 4-edge unroll ============
__global__ void gather_agg_bf(const unsigned short* __restrict__ h,
                              const int* __restrict__ rowptr, const int* __restrict__ col,
                              unsigned short* __restrict__ agg, int N) {
    int t = blockIdx.x * blockDim.x + threadIdx.x;
    int node = t >> 4;
    if (node >= N) return;
    int part = (t & 15) * 8;
    const unsigned short* hp = h + part;
    const int beg = rowptr[node], end = rowptr[node + 1];

    float acc[8];
    {
        uint4 sv = *reinterpret_cast<const uint4*>(hp + (size_t)node * 128);
        acc[0] = bfLo(sv.x); acc[1] = bfHi(sv.x);
        acc[2] = bfLo(sv.y); acc[3] = bfHi(sv.y);
        acc[4] = bfLo(sv.z); acc[5] = bfHi(sv.z);
        acc[6] = bfLo(sv.w); acc[7] = bfHi(sv.w);
    }
    int e = beg;
    for (; e + 3 < end; e += 4) {
        int s0 = col[e], s1 = col[e + 1], s2 = col[e + 2], s3 = col[e + 3];
        uint4 v0 = *reinterpret_cast<const uint4*>(hp + (size_t)s0 * 128);
        uint4 v1 = *reinterpret_cast<const uint4*>(hp + (size_t)s1 * 128);
        uint4 v2 = *reinterpret_cast<const uint4*>(hp + (size_t)s2 * 128);
        uint4 v3 = *reinterpret_cast<const uint4*>(hp + (size_t)s3 * 128);
        accRow(acc, v0); accRow(acc, v1); accRow(acc, v2); accRow(acc, v3);
    }
    for (; e < end; ++e)
        accRow(acc, *reinterpret_cast<const uint4*>(hp + (size_t)col[e] * 128));

    uint4 o;
    o.x = (unsigned int)f2bf(acc[0]) | ((unsigned int)f2bf(acc[1]) << 16);
    o.y = (unsigned int)f2bf(acc[2]) | ((unsigned int)f2bf(acc[3]) << 16);
    o.z = (unsigned int)f2bf(acc[4]) | ((unsigned int)f2bf(acc[5]) << 16);
    o.w = (unsigned int)f2bf(acc[6]) | ((unsigned int)f2bf(acc[7]) << 16);
    *reinterpret_cast<uint4*>(agg + (size_t)node * 128 + part) = o;
}

// ============ BN+ReLU-fused gather (layer 2), 4-edge unroll ============
__global__ void gather_bn_agg(const unsigned short* __restrict__ raw,
                              const float* __restrict__ sumsPad, const float* __restrict__ sqsPad,
                              const float* __restrict__ g, const float* __restrict__ be,
                              const int* __restrict__ rowptr, const int* __restrict__ col,
                              unsigned short* __restrict__ agg, int N, float invN) {
    int t = blockIdx.x * blockDim.x + threadIdx.x;
    int node = t >> 4;
    if (node >= N) return;
    int part = (t & 15) * 8;
    const unsigned short* rp = raw + part;
    float a8[8], c8[8];
#pragma unroll
    for (int k = 0; k < 8; ++k) {
        int c = part + k;
        float m = sumsPad[c * 16] * invN;
        float v = sqsPad[c * 16] * invN - m * m;
        float ai = g[c] * rsqrtf(v + BN_EPS);
        a8[k] = ai;
        c8[k] = be[c] - m * ai;
    }
    const int beg = rowptr[node], end = rowptr[node + 1];
    float acc[8] = {0.f, 0.f, 0.f, 0.f, 0.f, 0.f, 0.f, 0.f};
    accRowBN(acc, *reinterpret_cast<const uint4*>(rp + (size_t)node * 128), a8, c8);  // self
    int e = beg;
    for (; e + 3 < end; e += 4) {
        int s0 = col[e], s1 = col[e + 1], s2 = col[e + 2], s3 = col[e + 3];
        uint4 v0 = *reinterpret_cast<const uint4*>(rp + (size_t)s0 * 128);
        uint4 v1 = *reinterpret_cast<const uint4*>(rp + (size_t)s1 * 128);
        uint4 v2 = *reinterpret_cast<const uint4*>(rp + (size_t)s2 * 128);
        uint4 v3 = *reinterpret_cast<const uint4*>(rp + (size_t)s3 * 128);
        accRowBN(acc, v0, a8, c8); accRowBN(acc, v1, a8, c8);
        accRowBN(acc, v2, a8, c8); accRowBN(acc, v3, a8, c8);
    }
    for (; e < end; ++e)
        accRowBN(acc, *reinterpret_cast<const uint4*>(rp + (size_t)col[e] * 128), a8, c8);

    uint4 o;
    o.x = (unsigned int)f2bf(acc[0]) | ((unsigned int)f2bf(acc[1]) << 16);
    o.y = (unsigned int)f2bf(acc[2]) | ((unsigned int)f2bf(acc[3]) << 16);
    o.z = (unsigned int)f2bf(acc[4]) | ((unsigned int)f2bf(acc[5]) << 16);
    o.w = (unsigned int)f2bf(acc[6]) | ((unsigned int)f2bf(acc[7]) << 16);
    *reinterpret_cast<uint4*>(agg + (size_t)node * 128 + part) = o;
}

// ========== MFMA GEMM (NOUT=128) + bias + fused column stats; bf16 raw out ==========
__global__ __launch_bounds__(256) void gemm128_stats(const unsigned short* __restrict__ A,
                                                     const unsigned short* __restrict__ Wsw,
                                                     const float* __restrict__ bias,
                                                     unsigned short* __restrict__ outb,
                                                     float* __restrict__ sumsPad,
                                                     float* __restrict__ sqsPad, int N) {
    __shared__ float red[2][4][128];
    const int lane = threadIdx.x & 63;
    const int w = threadIdx.x >> 6;
    const int r0 = blockIdx.x * 64 + w * 16;
    int arow = r0 + (lane & 15);
    if (arow >= N) arow = N - 1;
    const int kb = lane >> 4;
    const unsigned short* ap = A + (size_t)arow * 128 + kb * 8;

    bf16x8 a[4];
#pragma unroll
    for (int q = 0; q < 4; ++q) a[q] = *reinterpret_cast<const bf16x8*>(ap + q * 32);

    f32x4 acc[8];
#pragma unroll
    for (int ct = 0; ct < 8; ++ct) acc[ct] = (f32x4){0.f, 0.f, 0.f, 0.f};

    const bf16x8* wp = reinterpret_cast<const bf16x8*>(Wsw) + lane;
#pragma unroll
    for (int ct = 0; ct < 8; ++ct)
#pragma unroll
        for (int q = 0; q < 4; ++q)
            acc[ct] = __builtin_amdgcn_mfma_f32_16x16x32_bf16(a[q], wp[(ct * 4 + q) * 64],
                                                              acc[ct], 0, 0, 0);

    const int crow0 = r0 + (lane >> 4) * 4;
    const int ccol = lane & 15;
#pragma unroll
    for (int ct = 0; ct < 8; ++ct) {
        int c = ct * 16 + ccol;
        float bv = bias[c];
        float s = 0.f, qq = 0.f;
#pragma unroll
        for (int j = 0; j < 4; ++j) {
            int r = crow0 + j;
            if (r < N) {
                float o = acc[ct][j] + bv;
                outb[(size_t)r * 128 + c] = f2bf(o);
                s += o; qq += o * o;
            }
        }
        s += __shfl_xor(s, 16); s += __shfl_xor(s, 32);
        qq += __shfl_xor(qq, 16); qq += __shfl_xor(qq, 32);
        if (lane < 16) { red[0][w][c] = s; red[1][w][c] = qq; }
    }
    __syncthreads();
    int tid = threadIdx.x;
    if (tid < 128) {
        float S = red[0][0][tid] + red[0][1][tid] + red[0][2][tid] + red[0][3][tid];
        atomicAdd(&sumsPad[tid * 16], S);
    } else {
        int c = tid - 128;
        float Q = red[1][0][c] + red[1][1][c] + red[1][2][c] + red[1][3][c];
        atomicAdd(&sqsPad[c * 16], Q);
    }
}

// ========== MFMA GEMM (NOUT=64) with inline BN2+ReLU on A; M = relu(bn(raw)) @ W3 (NO bias) ==========
__global__ __launch_bounds__(256) void gemm64_bn(const unsigned short* __restrict__ raw,
                                                 const float* __restrict__ sumsPad,
                                                 const float* __restrict__ sqsPad,
                                                 const float* __restrict__ g,
                                                 const float* __restrict__ be,
                                                 const unsigned short* __restrict__ Wsw,
                                                 unsigned short* __restrict__ M, int N,
                                                 float invN) {
    const int lane = threadIdx.x & 63;
    const int w = threadIdx.x >> 6;
    const int r0 = blockIdx.x * 64 + w * 16;
    int arow = r0 + (lane & 15);
    if (arow >= N) arow = N - 1;
    const int kb = lane >> 4;
    const unsigned short* ap = raw + (size_t)arow * 128 + kb * 8;

    bf16x8 a[4];
#pragma unroll
    for (int q = 0; q < 4; ++q) {
        uint4 rv = *reinterpret_cast<const uint4*>(ap + q * 32);
        float hh[8] = {bfLo(rv.x), bfHi(rv.x), bfLo(rv.y), bfHi(rv.y),
                       bfLo(rv.z), bfHi(rv.z), bfLo(rv.w), bfHi(rv.w)};
        unsigned int pk[4];
#pragma unroll
        for (int p = 0; p < 4; ++p) {
            unsigned int lohi[2];
#pragma unroll
            for (int hl = 0; hl < 2; ++hl) {
                int j = p * 2 + hl;
                int c = q * 32 + kb * 8 + j;
                float mcol = sumsPad[c * 16] * invN;
                float var = sqsPad[c * 16] * invN - mcol * mcol;
                float ai = g[c] * rsqrtf(var + BN_EPS);
                float ci = be[c] - mcol * ai;
                lohi[hl] = f2bf(fmaxf(fmaf(hh[j], ai, ci), 0.f));
            }
            pk[p] = lohi[0] | (lohi[1] << 16);
        }
        uint4 hp;
        hp.x = pk[0]; hp.y = pk[1]; hp.z = pk[2]; hp.w = pk[3];
        a[q] = *reinterpret_cast<bf16x8*>(&hp);
    }

    f32x4 acc[4];
#pragma unroll
    for (int ct = 0; ct < 4; ++ct) acc[ct] = (f32x4){0.f, 0.f, 0.f, 0.f};

    const bf16x8* wp = reinterpret_cast<const bf16x8*>(Wsw) + lane;
#pragma unroll
    for (int ct = 0; ct < 4; ++ct)
#pragma unroll
        for (int q = 0; q < 4; ++q)
            acc[ct] = __builtin_amdgcn_mfma_f32_16x16x32_bf16(a[q], wp[(ct * 4 + q) * 64],
                                                              acc[ct], 0, 0, 0);

    const int crow0 = r0 + (lane >> 4) * 4;
    const int ccol = lane & 15;
#pragma unroll
    for (int ct = 0; ct < 4; ++ct) {
        int c = ct * 16 + ccol;
#pragma unroll
        for (int j = 0; j < 4; ++j) {
            int r = crow0 + j;
            if (r < N) M[(size_t)r * 64 + c] = f2bf(acc[ct][j]);
        }
    }
}

// ========== layer-3 gather on M (64-wide) + bias + log_softmax; 8 lanes/node, 4-edge unroll ==========
__global__ void gather64_lsm(const unsigned short* __restrict__ M,
                             const int* __restrict__ rowptr, const int* __restrict__ col,
                             const float* __restrict__ bias, float* __restrict__ out, int N) {
    int t = blockIdx.x * blockDim.x + threadIdx.x;
    int node = t >> 3;
    if (node >= N) return;
    int part = (t & 7) * 8;
    const unsigned short* mp = M + part;
    const int beg = rowptr[node], end = rowptr[node + 1];

    float acc[8];
    {
        uint4 sv = *reinterpret_cast<const uint4*>(mp + (size_t)node * 64);
        acc[0] = bfLo(sv.x); acc[1] = bfHi(sv.x);
        acc[2] = bfLo(sv.y); acc[3] = bfHi(sv.y);
        acc[4] = bfLo(sv.z); acc[5] = bfHi(sv.z);
        acc[6] = bfLo(sv.w); acc[7] = bfHi(sv.w);
    }
    int e = beg;
    for (; e + 3 < end; e += 4) {
        int s0 = col[e], s1 = col[e + 1], s2 = col[e + 2], s3 = col[e + 3];
        uint4 v0 = *reinterpret_cast<const uint4*>(mp + (size_t)s0 * 64);
        uint4 v1 = *reinterpret_cast<const uint4*>(mp + (size_t)s1 * 64);
        uint4 v2 = *reinterpret_cast<const uint4*>(mp + (size_t)s2 * 64);
        uint4 v3 = *reinterpret_cast<const uint4*>(mp + (size_t)s3 * 64);
        accRow(acc, v0); accRow(acc, v1); accRow(acc, v2); accRow(acc, v3);
    }
    for (; e < end; ++e)
        accRow(acc, *reinterpret_cast<const uint4*>(mp + (size_t)col[e] * 64));

#pragma unroll
    for (int k = 0; k < 8; ++k) acc[k] += bias[part + k];

    float m = acc[0];
#pragma unroll
    for (int k = 1; k < 8; ++k) m = fmaxf(m, acc[k]);
#pragma unroll
    for (int off = 1; off < 8; off <<= 1) m = fmaxf(m, __shfl_xor(m, off));
    float s = 0.f;
#pragma unroll
    for (int k = 0; k < 8; ++k) s += __expf(acc[k] - m);
#pragma unroll
    for (int off = 1; off < 8; off <<= 1) s += __shfl_xor(s, off);
    float ml = m + __logf(s);

    float4 o0, o1;
    o0.x = acc[0] - ml; o0.y = acc[1] - ml; o0.z = acc[2] - ml; o0.w = acc[3] - ml;
    o1.x = acc[4] - ml; o1.y = acc[5] - ml; o1.z = acc[6] - ml; o1.w = acc[7] - ml;
    float* op = out + (size_t)node * 64 + part;
    *reinterpret_cast<float4*>(op) = o0;
    *reinterpret_cast<float4*>(op + 4) = o1;
}

extern "C" void kernel_launch(void* const* d_in, const int* in_sizes, int n_in,
                              void* d_out, int out_size, void* d_ws, size_t ws_size,
                              hipStream_t stream) {
    const float* x   = (const float*)d_in[0];
    const int*   ei  = (const int*)d_in[1];
    const float* W1  = (const float*)d_in[2];
    const float* b1  = (const float*)d_in[3];
    const float* g1  = (const float*)d_in[4];
    const float* be1 = (const float*)d_in[5];
    const float* W2  = (const float*)d_in[6];
    const float* b2  = (const float*)d_in[7];
    const float* g2  = (const float*)d_in[8];
    const float* be2 = (const float*)d_in[9];
    const float* W3  = (const float*)d_in[10];
    const float* b3  = (const float*)d_in[11];

    const int N = in_sizes[0] / 128;
    const int E = in_sizes[1] / 2;
    const int* src = ei;
    const int* dst = ei + E;

    // ---- workspace carve-up; [statsPad|cnts|deg] is one memset region ----
    float* statsPad = (float*)d_ws;                 // 4 x 2048 (stride-16 cols)
    float* sums1 = statsPad;
    float* sqs1  = statsPad + 2048;
    float* sums2 = statsPad + 4096;
    float* sqs2  = statsPad + 6144;
    int* cnts   = (int*)(statsPad + 8192);          // 64 (grid-barrier counters)
    int* deg    = cnts + 64;                        // N
    int* pos    = deg + N;                          // N
    int* rowptr = pos + N;                          // N+1
    int* bsum   = rowptr + N + 1;                   // 256
    int* colidx = bsum + 256;                       // E
    unsigned short* hb   = (unsigned short*)(colidx + E);   // N*128 bf16 (x)
    unsigned short* rawb = hb + (size_t)N * 128;            // N*128 bf16 (gemm raw out)
    unsigned short* agb  = rawb + (size_t)N * 128;          // N*128 bf16 (agg)
    unsigned short* m3   = agb + (size_t)N * 128;           // N*64 bf16 (layer3 pre-agg)
    unsigned short* w1s  = m3 + (size_t)N * 64;             // 16384
    unsigned short* w2s  = w1s + 16384;                     // 16384
    unsigned short* w3s  = w2s + 16384;                     // 8192

    const int nChunks = (N + 255) / 256;
    const int eBlocks = (E + 255) / 256;
    const int gemmBlocks = (N + 63) / 64;
    const int gatherBlocks = (N * 16 + 255) / 256;
    const int gather64Blocks = (N * 8 + 255) / 256;
    const int total4 = N * 128 / 4;
    const float invN = 1.0f / N;

    // ---- one memset: stats + counters + deg ----
    hipMemsetAsync(statsPad, 0, 8192 * sizeof(float) + (64 + (size_t)N) * sizeof(int), stream);

    // ---- prep (x->bf16, W swizzle, degree hist); merged scan; wide fill ----
    convert_prep_hist<<<2048, 256, 0, stream>>>(x, hb, total4, W1, W2, W3, w1s, w2s, w3s,
                                                dst, deg, E);
    build_rowptr<<<nChunks, 256, 0, stream>>>(deg, rowptr, pos, bsum, cnts, N, E, nChunks);
    fill_kernel<<<eBlocks, 256, 0, stream>>>(src, dst, pos, colidx, E);

    // ---- layer 1 ----
    gather_agg_bf<<<gatherBlocks, 256, 0, stream>>>(hb, rowptr, colidx, agb, N);
    gemm128_stats<<<gemmBlocks, 256, 0, stream>>>(agb, w1s, b1, rawb, sums1, sqs1, N);

    // ---- layer 2 (BN1+ReLU fused into gather) ----
    gather_bn_agg<<<gatherBlocks, 256, 0, stream>>>(rawb, sums1, sqs1, g1, be1, rowptr, colidx,
                                                    agb, N, invN);
    gemm128_stats<<<gemmBlocks, 256, 0, stream>>>(agb, w2s, b2, rawb, sums2, sqs2, N);

    // ---- layer 3: GEMM first (BN2+ReLU inline), then 64-wide gather + bias + lsm ----
    gemm64_bn<<<gemmBlocks, 256, 0, stream>>>(rawb, sums2, sqs2, g2, be2, w3s, m3, N, invN);
    gather64_lsm<<<gather64Blocks, 256, 0, stream>>>(m3, rowptr, colidx, b3, (float*)d_out, N);
}